// Round 3
// baseline (370.803 us; speedup 1.0000x reference)
//
#include <hip/hip_runtime.h>
#include <stdint.h>

typedef __attribute__((ext_vector_type(8))) __bf16 bf16x8;
typedef __attribute__((ext_vector_type(4))) __bf16 bf16x4;
typedef __attribute__((ext_vector_type(4))) float f32x4;

// ws/scal layout: scal[0]=Ssum [1]=g4*log2e [3]=sumsq [8]=cnt_outs [9]=cnt_gram_waves

// ---------------- outs GEMM, LDS-free, fused sq/colsum/bandwidth ----------------
// tile 64(M) x 128(N), grid (4, 64) = 256 blocks. 4 waves in 2x2: wave = 32M x 64N.
// Fragments loaded directly from global (fp32 -> bf16 cvt in regs). No barriers in loop.
__global__ __launch_bounds__(256) void k_outs(const float* __restrict__ x,
                                              const float* __restrict__ W,
                                              const float* __restrict__ bias,
                                              __bf16* __restrict__ totalbf,
                                              float* __restrict__ sq,
                                              float* __restrict__ colsum,
                                              float* __restrict__ scal) {
  __shared__ float red[256];
  __shared__ int lastflag;
  const int bj = blockIdx.x;       // 0..3  (N/128)
  const int bi = blockIdx.y;       // 0..63 (M/64)
  const int t = threadIdx.x;
  const int wid = t >> 6, lane = t & 63;
  const int wr = wid >> 1, wc = wid & 1;
  const int n16 = lane & 15, q = lane >> 4;

  const float* pa[2];
  const float* pb[4];
  for (int f = 0; f < 2; ++f)
    pa[f] = x + (size_t)(bi * 64 + wr * 32 + f * 16 + n16) * 512 + q * 8;
  for (int f = 0; f < 4; ++f)
    pb[f] = W + (size_t)(bj * 128 + wc * 64 + f * 16 + n16) * 512 + q * 8;

  f32x4 acc[2][4];
  f32x4 zero = {0.f, 0.f, 0.f, 0.f};
  for (int i = 0; i < 2; ++i)
    for (int j = 0; j < 4; ++j) acc[i][j] = zero;

#pragma unroll 4
  for (int ks = 0; ks < 16; ++ks) {
    bf16x8 af[2], bfr[4];
    for (int f = 0; f < 2; ++f) {
      float4 lo = *(const float4*)(pa[f] + ks * 32);
      float4 hi = *(const float4*)(pa[f] + ks * 32 + 4);
      bf16x8 v = {(__bf16)lo.x, (__bf16)lo.y, (__bf16)lo.z, (__bf16)lo.w,
                  (__bf16)hi.x, (__bf16)hi.y, (__bf16)hi.z, (__bf16)hi.w};
      af[f] = v;
    }
    for (int f = 0; f < 4; ++f) {
      float4 lo = *(const float4*)(pb[f] + ks * 32);
      float4 hi = *(const float4*)(pb[f] + ks * 32 + 4);
      bf16x8 v = {(__bf16)lo.x, (__bf16)lo.y, (__bf16)lo.z, (__bf16)lo.w,
                  (__bf16)hi.x, (__bf16)hi.y, (__bf16)hi.z, (__bf16)hi.w};
      bfr[f] = v;
    }
    for (int fr = 0; fr < 2; ++fr)
      for (int fc = 0; fc < 4; ++fc)
        acc[fr][fc] = __builtin_amdgcn_mfma_f32_16x16x32_bf16(af[fr], bfr[fc], acc[fr][fc], 0, 0, 0);
  }

  // ---- epilogue: +bias, bf16 store, fused sq / colsum / sumsq ----
  const int l = bj >> 1;
  float bv[4];
  for (int fc = 0; fc < 4; ++fc)
    bv[fc] = bias[bj * 128 + wc * 64 + fc * 16 + n16];

  float lane_ss = 0.f;
  float colpart[4] = {0.f, 0.f, 0.f, 0.f};
  for (int fr = 0; fr < 2; ++fr) {
    for (int r = 0; r < 4; ++r) {
      int mrow = bi * 64 + wr * 32 + fr * 16 + q * 4 + r;
      float rowpart = 0.f;
      for (int fc = 0; fc < 4; ++fc) {
        int o = (bj & 1) * 128 + wc * 64 + fc * 16 + n16;
        float v = acc[fr][fc][r] + bv[fc];
        __bf16 h = (__bf16)v;
        totalbf[(size_t)(l * 4096 + mrow) * 256 + o] = h;
        float vr = (float)h;
        rowpart += vr * vr;
        lane_ss += vr * vr;
        colpart[fc] += vr;
      }
      for (int off = 1; off < 16; off <<= 1) rowpart += __shfl_xor(rowpart, off, 64);
      if (n16 == 0) atomicAdd(&sq[l * 4096 + mrow], rowpart);
    }
  }
  // colsum: reduce over q (lanes differing in bits 4,5)
  for (int fc = 0; fc < 4; ++fc) {
    colpart[fc] += __shfl_xor(colpart[fc], 16, 64);
    colpart[fc] += __shfl_xor(colpart[fc], 32, 64);
  }
  if (q == 0)
    for (int fc = 0; fc < 4; ++fc)
      atomicAdd(&colsum[(bj & 1) * 128 + wc * 64 + fc * 16 + n16], colpart[fc]);
  for (int off = 1; off < 64; off <<= 1) lane_ss += __shfl_xor(lane_ss, off, 64);
  if (lane == 0) atomicAdd(&scal[3], lane_ss);

  __threadfence();
  __syncthreads();
  if (t == 0) lastflag = (atomicAdd((int*)&scal[8], 1) == 255);
  __syncthreads();
  if (lastflag) {
    float c = atomicAdd(&colsum[t], 0.f);   // device-coherent read
    red[t] = c * c;
    __syncthreads();
    for (int off = 128; off; off >>= 1) { if (t < off) red[t] += red[t + off]; __syncthreads(); }
    if (t == 0) {
      float sumsq = atomicAdd(&scal[3], 0.f);
      double sumdist = 2.0 * 8192.0 * (double)sumsq - 2.0 * (double)red[0];
      double bw = sumdist / (8192.0 * 8192.0 - 8192.0) / 4.0;  // / KERNEL_MUL^(5//2)
      scal[1] = (float)(1.4426950408889634 / (bw * 16.0));     // g4 * log2(e)
    }
  }
}

// ---------------- combine with fused gates: one wave per row ------------------
__global__ __launch_bounds__(256) void k_combine(const float* __restrict__ x,
                                                 const float* __restrict__ Waux,
                                                 const float* __restrict__ baux,
                                                 const __bf16* __restrict__ tot,
                                                 float* __restrict__ out) {
  const int wid = threadIdx.x >> 6;
  const int lane = threadIdx.x & 63;
  const int row = blockIdx.x * 4 + wid;
  const float4* xr = (const float4*)(x + (size_t)row * 512);
  const float4* w0 = (const float4*)(Waux);
  const float4* w1 = (const float4*)(Waux + 512);
  float p0 = 0.f, p1 = 0.f;
  for (int c = lane; c < 128; c += 64) {
    float4 xv = xr[c];
    float4 a = w0[c], b = w1[c];
    p0 += xv.x * a.x + xv.y * a.y + xv.z * a.z + xv.w * a.w;
    p1 += xv.x * b.x + xv.y * b.y + xv.z * b.z + xv.w * b.w;
  }
  for (int off = 1; off < 64; off <<= 1) {
    p0 += __shfl_xor(p0, off, 64);
    p1 += __shfl_xor(p1, off, 64);
  }
  p0 += baux[0]; p1 += baux[1];
  float m = fmaxf(p0, p1);
  float e0 = __expf(p0 - m), e1 = __expf(p1 - m);
  float inv = 1.f / (e0 + e1);
  float g0 = e0 * inv, g1 = e1 * inv;

  int oc = lane * 4;
  bf16x4 v0 = *(const bf16x4*)(tot + (size_t)row * 256 + oc);
  bf16x4 v1 = *(const bf16x4*)(tot + (size_t)(4096 + row) * 256 + oc);
  float4 r;
  r.x = g0 * (float)v0[0] + g1 * (float)v1[0];
  r.y = g0 * (float)v0[1] + g1 * (float)v1[1];
  r.z = g0 * (float)v0[2] + g1 * (float)v1[2];
  r.w = g0 * (float)v0[3] + g1 * (float)v1[3];
  *(float4*)(out + (size_t)row * 256 + oc) = r;
}

// ---------------- Gram + fused multi-bandwidth kernel sum ---------------------
// LDS-free, barrier-free: fragments loaded directly from global (tot is L2-hot).
// 2080 triangular 128x128 tiles; register double-buffer over 8 K-chunks of 32.
__global__ __launch_bounds__(256, 3) void k_gram(const __bf16* __restrict__ tot,
                                                 const float* __restrict__ sq,
                                                 const float* __restrict__ scal,
                                                 float* __restrict__ Ssum,
                                                 float* __restrict__ out) {
  const int t = threadIdx.x;
  const int wid = t >> 6, lane = t & 63;
  const int wr = wid >> 1, wc = wid & 1;
  const int n16 = lane & 15, q = lane >> 4;

  // triangular decode: blockIdx.x -> (ti, tj), ti <= tj
  int m = 2079 - (int)blockIdx.x;
  int n = (int)((sqrtf(8.f * (float)m + 1.f) - 1.f) * 0.5f);
  while ((n + 1) * (n + 2) / 2 <= m) ++n;
  while (n * (n + 1) / 2 > m) --n;
  const int ti = 63 - n;
  const int tj = 63 - (m - n * (n + 1) / 2);

  const __bf16* pa[4];
  const __bf16* pb[4];
  for (int f = 0; f < 4; ++f) {
    pa[f] = tot + (size_t)(ti * 128 + wr * 64 + f * 16 + n16) * 256 + q * 8;
    pb[f] = tot + (size_t)(tj * 128 + wc * 64 + f * 16 + n16) * 256 + q * 8;
  }

  f32x4 acc[4][4];
  f32x4 zero = {0.f, 0.f, 0.f, 0.f};
  for (int i = 0; i < 4; ++i)
    for (int j = 0; j < 4; ++j) acc[i][j] = zero;

  bf16x8 a0[4], b0[4], a1[4], b1[4];
  for (int f = 0; f < 4; ++f) {
    a0[f] = *(const bf16x8*)(pa[f]);
    b0[f] = *(const bf16x8*)(pb[f]);
  }
#pragma unroll
  for (int ks = 0; ks < 8; ks += 2) {
    if (ks + 1 < 8)
      for (int f = 0; f < 4; ++f) {
        a1[f] = *(const bf16x8*)(pa[f] + (ks + 1) * 32);
        b1[f] = *(const bf16x8*)(pb[f] + (ks + 1) * 32);
      }
    for (int fr = 0; fr < 4; ++fr)
      for (int fc = 0; fc < 4; ++fc)
        acc[fr][fc] = __builtin_amdgcn_mfma_f32_16x16x32_bf16(a0[fr], b0[fc], acc[fr][fc], 0, 0, 0);
    if (ks + 2 < 8)
      for (int f = 0; f < 4; ++f) {
        a0[f] = *(const bf16x8*)(pa[f] + (ks + 2) * 32);
        b0[f] = *(const bf16x8*)(pb[f] + (ks + 2) * 32);
      }
    if (ks + 1 < 8)
      for (int fr = 0; fr < 4; ++fr)
        for (int fc = 0; fc < 4; ++fc)
          acc[fr][fc] = __builtin_amdgcn_mfma_f32_16x16x32_bf16(a1[fr], b1[fc], acc[fr][fc], 0, 0, 0);
  }

  // epilogue: u = exp2(fma(2g, dot, ci+cj)); ksum = u+u^2+u^4+u^8+u^16
  const float g = scal[1];
  const float g2 = 2.f * g;
  float cj[4];
  for (int fc = 0; fc < 4; ++fc)
    cj[fc] = -g * sq[tj * 128 + wc * 64 + fc * 16 + n16];

  float lsum = 0.f;
  for (int fr = 0; fr < 4; ++fr) {
    for (int r = 0; r < 4; ++r) {
      float ci = -g * sq[ti * 128 + wr * 64 + fr * 16 + q * 4 + r];
      for (int fc = 0; fc < 4; ++fc) {
        float p = fmaf(g2, acc[fr][fc][r], ci + cj[fc]);
        float u = exp2f(p);
        float u2 = u * u, u4 = u2 * u2, u8 = u4 * u4, u16 = u8 * u8;
        lsum += (u + u2) + (u4 + u8) + u16;
      }
    }
  }
  for (int off = 1; off < 64; off <<= 1) lsum += __shfl_xor(lsum, off, 64);
  if (lane == 0) {
    float sgn = ((ti < 32) == (tj < 32)) ? 1.f : -1.f;
    float wgt = (ti == tj) ? sgn : 2.f * sgn;
    atomicAdd(Ssum, wgt * lsum);
    __threadfence();
    int old = atomicAdd((int*)(Ssum + 9), 1);   // scal[9]: wave counter
    if (old == 2080 * 4 - 1) {
      float S = atomicAdd(Ssum, 0.f);
      out[1048576] = -(S / 16777216.0f);
    }
  }
}

extern "C" void kernel_launch(void* const* d_in, const int* in_sizes, int n_in,
                              void* d_out, int out_size, void* d_ws, size_t ws_size,
                              hipStream_t stream) {
  const float* x    = (const float*)d_in[0];
  const float* Waux = (const float*)d_in[1];
  const float* baux = (const float*)d_in[2];
  const float* W    = (const float*)d_in[3];
  const float* bias = (const float*)d_in[4];
  float* out = (float*)d_out;

  char* ws = (char*)d_ws;
  __bf16* totalbf = (__bf16*)ws;                    // 8192*256*2 = 4,194,304 B
  float* sq      = (float*)(ws + 4194304);          // 8192 f32
  float* colsum  = (float*)(ws + 4227072);          // 256 f32
  float* scal    = (float*)(ws + 4228096);          // 16 f32

  // zero sq + colsum + scal (sq is now accumulated via atomics)
  hipMemsetAsync(ws + 4194304, 0, 32768 + 1024 + 64, stream);

  k_outs<<<dim3(4, 64), 256, 0, stream>>>(x, W, bias, totalbf, sq, colsum, scal);
  k_combine<<<1024, 256, 0, stream>>>(x, Waux, baux, totalbf, out);
  k_gram<<<2080, 256, 0, stream>>>(totalbf, sq, scal, scal, out);
}

// Round 4
// 281.568 us; speedup vs baseline: 1.3169x; 1.3169x over previous
//
#include <hip/hip_runtime.h>
#include <stdint.h>

typedef __attribute__((ext_vector_type(8))) __bf16 bf16x8;
typedef __attribute__((ext_vector_type(4))) __bf16 bf16x4;
typedef __attribute__((ext_vector_type(4))) float f32x4;

// ws/scal layout: scal[0]=Ssum [1]=g4*log2e [3]=sumsq [8]=cnt_outs [9]=cnt_gram

// ---------------- outs GEMM (R2 padded-LDS structure) + fused sq/colsum/bw ----
// grid (4, 32): tile 128(M) x 128(N), 4 waves 2x2, wave 64x64.
__global__ __launch_bounds__(256) void k_outs(const float* __restrict__ x,
                                              const float* __restrict__ W,
                                              const float* __restrict__ bias,
                                              __bf16* __restrict__ totalbf,
                                              float* __restrict__ sq,
                                              float* __restrict__ colsum,
                                              float* __restrict__ scal) {
  __shared__ __bf16 As[128][72];   // +8 pad: rotates banks, ~free
  __shared__ __bf16 Bs[128][72];
  __shared__ float red[256];
  __shared__ int lastflag;
  const int bj = blockIdx.x;   // 0..3  (N tiles)
  const int bi = blockIdx.y;   // 0..31 (M tiles)
  const int t = threadIdx.x;
  const int wid = t >> 6, lane = t & 63;
  const int wr = wid >> 1, wc = wid & 1;
  const int n16 = lane & 15, q = lane >> 4;

  f32x4 acc[4][4];
  f32x4 zero = {0.f, 0.f, 0.f, 0.f};
  for (int i = 0; i < 4; ++i)
    for (int j = 0; j < 4; ++j) acc[i][j] = zero;

  const int arow0 = bi * 128;
  const int brow0 = bj * 128;

  for (int kc = 0; kc < 512; kc += 64) {
    for (int p = 0; p < 8; ++p) {
      int e = p * 256 + t;            // 0..2047
      int row = e >> 4;               // 0..127
      int c4 = (e & 15) << 2;         // 0..60
      float4 va = *(const float4*)(x + (size_t)(arow0 + row) * 512 + kc + c4);
      bf16x4 ba = {(__bf16)va.x, (__bf16)va.y, (__bf16)va.z, (__bf16)va.w};
      *(bf16x4*)&As[row][c4] = ba;
      float4 vb = *(const float4*)(W + (size_t)(brow0 + row) * 512 + kc + c4);
      bf16x4 bb = {(__bf16)vb.x, (__bf16)vb.y, (__bf16)vb.z, (__bf16)vb.w};
      *(bf16x4*)&Bs[row][c4] = bb;
    }
    __syncthreads();
    for (int ks = 0; ks < 2; ++ks) {
      bf16x8 af[4], bfr[4];
      for (int f = 0; f < 4; ++f) {
        af[f]  = *(const bf16x8*)&As[wr * 64 + f * 16 + n16][ks * 32 + q * 8];
        bfr[f] = *(const bf16x8*)&Bs[wc * 64 + f * 16 + n16][ks * 32 + q * 8];
      }
      for (int fr = 0; fr < 4; ++fr)
        for (int fc = 0; fc < 4; ++fc)
          acc[fr][fc] = __builtin_amdgcn_mfma_f32_16x16x32_bf16(af[fr], bfr[fc], acc[fr][fc], 0, 0, 0);
    }
    __syncthreads();
  }

  // epilogue: +bias, bf16 store, fused sq / colsum / sumsq
  const int l = bj >> 1;
  float bv[4];
  for (int fc = 0; fc < 4; ++fc)
    bv[fc] = bias[bj * 128 + wc * 64 + fc * 16 + n16];

  float lane_ss = 0.f;
  float colpart[4] = {0.f, 0.f, 0.f, 0.f};
  for (int fr = 0; fr < 4; ++fr) {
    for (int r = 0; r < 4; ++r) {
      int mrow = bi * 128 + wr * 64 + fr * 16 + q * 4 + r;
      float rowpart = 0.f;
      for (int fc = 0; fc < 4; ++fc) {
        int o = (bj & 1) * 128 + wc * 64 + fc * 16 + n16;
        float v = acc[fr][fc][r] + bv[fc];
        __bf16 h = (__bf16)v;
        totalbf[(size_t)(l * 4096 + mrow) * 256 + o] = h;
        float vr = (float)h;
        rowpart += vr * vr;
        lane_ss += vr * vr;
        colpart[fc] += vr;
      }
      for (int off = 1; off < 16; off <<= 1) rowpart += __shfl_xor(rowpart, off, 64);
      if (n16 == 0) atomicAdd(&sq[l * 4096 + mrow], rowpart);
    }
  }
  for (int fc = 0; fc < 4; ++fc) {
    colpart[fc] += __shfl_xor(colpart[fc], 16, 64);
    colpart[fc] += __shfl_xor(colpart[fc], 32, 64);
  }
  if (q == 0)
    for (int fc = 0; fc < 4; ++fc)
      atomicAdd(&colsum[(bj & 1) * 128 + wc * 64 + fc * 16 + n16], colpart[fc]);
  for (int off = 1; off < 64; off <<= 1) lane_ss += __shfl_xor(lane_ss, off, 64);
  if (lane == 0) atomicAdd(&scal[3], lane_ss);

  __threadfence();
  __syncthreads();
  if (t == 0) lastflag = (atomicAdd((int*)&scal[8], 1) == 127);
  __syncthreads();
  if (lastflag) {
    float c = atomicAdd(&colsum[t], 0.f);
    red[t] = c * c;
    __syncthreads();
    for (int off = 128; off; off >>= 1) { if (t < off) red[t] += red[t + off]; __syncthreads(); }
    if (t == 0) {
      float sumsq = atomicAdd(&scal[3], 0.f);
      double sumdist = 2.0 * 8192.0 * (double)sumsq - 2.0 * (double)red[0];
      double bw = sumdist / (8192.0 * 8192.0 - 8192.0) / 4.0;  // / KERNEL_MUL^(5//2)
      scal[1] = (float)(1.4426950408889634 / (bw * 16.0));     // g4 * log2(e)
    }
  }
}

// ---------------- combine with fused gates: one wave per row ------------------
__global__ __launch_bounds__(256) void k_combine(const float* __restrict__ x,
                                                 const float* __restrict__ Waux,
                                                 const float* __restrict__ baux,
                                                 const __bf16* __restrict__ tot,
                                                 float* __restrict__ out) {
  const int wid = threadIdx.x >> 6;
  const int lane = threadIdx.x & 63;
  const int row = blockIdx.x * 4 + wid;
  const float4* xr = (const float4*)(x + (size_t)row * 512);
  const float4* w0 = (const float4*)(Waux);
  const float4* w1 = (const float4*)(Waux + 512);
  float p0 = 0.f, p1 = 0.f;
  for (int c = lane; c < 128; c += 64) {
    float4 xv = xr[c];
    float4 a = w0[c], b = w1[c];
    p0 += xv.x * a.x + xv.y * a.y + xv.z * a.z + xv.w * a.w;
    p1 += xv.x * b.x + xv.y * b.y + xv.z * b.z + xv.w * b.w;
  }
  for (int off = 1; off < 64; off <<= 1) {
    p0 += __shfl_xor(p0, off, 64);
    p1 += __shfl_xor(p1, off, 64);
  }
  p0 += baux[0]; p1 += baux[1];
  float m = fmaxf(p0, p1);
  float e0 = __expf(p0 - m), e1 = __expf(p1 - m);
  float inv = 1.f / (e0 + e1);
  float g0 = e0 * inv, g1 = e1 * inv;

  int oc = lane * 4;
  bf16x4 v0 = *(const bf16x4*)(tot + (size_t)row * 256 + oc);
  bf16x4 v1 = *(const bf16x4*)(tot + (size_t)(4096 + row) * 256 + oc);
  float4 r;
  r.x = g0 * (float)v0[0] + g1 * (float)v1[0];
  r.y = g0 * (float)v0[1] + g1 * (float)v1[1];
  r.z = g0 * (float)v0[2] + g1 * (float)v1[2];
  r.w = g0 * (float)v0[3] + g1 * (float)v1[3];
  *(float4*)(out + (size_t)row * 256 + oc) = r;
}

// ---------------- Gram + fused multi-bandwidth kernel sum ---------------------
// Block tile 128(i) x 256(j); 4 waves 2x2; wave tile 64(i) x 128(j); BK=64.
// LDS XOR-swizzled at 16B: LDS[row][s] = G[row][(s^(row&7))*8..], conflict-free
// both on ds_write_b128 staging and ds_read_b128 fragment loads.
// Grid: 1056 triangular blocks over (ti in 0..63, tj in 0..31), ti <= 2*tj+1.
// Per-wave j-subtile jt = 2*tj+wc: skip if jt<ti, weight 1 if ==, 2 if >.
__global__ __launch_bounds__(256, 2) void k_gram(const __bf16* __restrict__ tot,
                                                 const float* __restrict__ sq,
                                                 const float* __restrict__ scal,
                                                 float* __restrict__ Ssum,
                                                 float* __restrict__ out) {
  __shared__ __bf16 As[128 * 64];   // 16 KB
  __shared__ __bf16 Bs[256 * 64];   // 32 KB
  const int t = threadIdx.x;
  const int wid = t >> 6, lane = t & 63;
  const int wr = wid >> 1, wc = wid & 1;
  const int n16 = lane & 15, q = lane >> 4;

  // decode blockIdx.x -> (tj, ti): cumulative C(tj) = tj^2 + tj
  int k = (int)blockIdx.x;
  int tj = (int)((sqrtf(4.f * (float)k + 1.f) - 1.f) * 0.5f);
  while ((tj + 1) * (tj + 2) <= k) ++tj;
  while (tj * (tj + 1) > k) --tj;
  const int ti = k - tj * (tj + 1);

  // staging address decomposition: thread t handles rows p*32+(t>>3), col byte (t&7)*16
  const int r8 = t >> 3;           // 0..31
  const int c8 = t & 7;            // 0..7
  const int s8 = c8 ^ (r8 & 7);    // swizzled LDS slot (constant per thread)
  const __bf16* gA = tot + (size_t)(ti * 128 + r8) * 256 + c8 * 8;
  const __bf16* gB = tot + (size_t)(tj * 256 + r8) * 256 + c8 * 8;
  __bf16* wA = &As[r8 * 64 + s8 * 8];
  __bf16* wB = &Bs[r8 * 64 + s8 * 8];

  f32x4 acc[4][8];
  f32x4 zero = {0.f, 0.f, 0.f, 0.f};
  for (int i = 0; i < 4; ++i)
    for (int j = 0; j < 8; ++j) acc[i][j] = zero;

  uint4 aregs[4], bregs[8];
  for (int p = 0; p < 4; ++p) aregs[p] = *(const uint4*)(gA + p * 32 * 256);
  for (int p = 0; p < 8; ++p) bregs[p] = *(const uint4*)(gB + p * 32 * 256);

  for (int kc = 0; kc < 4; ++kc) {
    __syncthreads();   // previous chunk's readers done
    for (int p = 0; p < 4; ++p) *(uint4*)(wA + p * 32 * 64) = aregs[p];
    for (int p = 0; p < 8; ++p) *(uint4*)(wB + p * 32 * 64) = bregs[p];
    __syncthreads();
    if (kc < 3) {   // prefetch next chunk; stays in flight during compute
      const __bf16* nA = gA + (kc + 1) * 64;
      const __bf16* nB = gB + (kc + 1) * 64;
      for (int p = 0; p < 4; ++p) aregs[p] = *(const uint4*)(nA + p * 32 * 256);
      for (int p = 0; p < 8; ++p) bregs[p] = *(const uint4*)(nB + p * 32 * 256);
    }
    for (int ks = 0; ks < 2; ++ks) {
      bf16x8 af[4];
      const int slot = ((ks * 4 + q) ^ (n16 & 7)) * 8;
      for (int f = 0; f < 4; ++f)
        af[f] = *(const bf16x8*)&As[(wr * 64 + f * 16 + n16) * 64 + slot];
      for (int fc = 0; fc < 8; ++fc) {
        bf16x8 bfrag = *(const bf16x8*)&Bs[(wc * 128 + fc * 16 + n16) * 64 + slot];
        for (int fr = 0; fr < 4; ++fr)
          acc[fr][fc] = __builtin_amdgcn_mfma_f32_16x16x32_bf16(af[fr], bfrag, acc[fr][fc], 0, 0, 0);
      }
    }
  }

  // epilogue (per wave; skip sub-diagonal waves)
  const int jt = 2 * tj + wc;
  if (jt >= ti) {
    const float g = scal[1];
    const float g2 = 2.f * g;
    float cj[8];
    for (int fc = 0; fc < 8; ++fc)
      cj[fc] = -g * sq[tj * 256 + wc * 128 + fc * 16 + n16];

    float lsum = 0.f;
    for (int fr = 0; fr < 4; ++fr) {
      for (int r = 0; r < 4; ++r) {
        float ci = -g * sq[ti * 128 + wr * 64 + fr * 16 + q * 4 + r];
        for (int fc = 0; fc < 8; ++fc) {
          float p = fmaf(g2, acc[fr][fc][r], ci + cj[fc]);
          float u = exp2f(p);
          float u2 = u * u, u4 = u2 * u2, u8 = u4 * u4, u16 = u8 * u8;
          lsum += ((u + u2) + (u4 + u8)) + u16;
        }
      }
    }
    for (int off = 1; off < 64; off <<= 1) lsum += __shfl_xor(lsum, off, 64);
    if (lane == 0) {
      float sgn = ((ti < 32) == (jt < 32)) ? 1.f : -1.f;
      float wgt = (jt == ti) ? sgn : 2.f * sgn;
      atomicAdd(Ssum, wgt * lsum);
      __threadfence();
      int old = atomicAdd((int*)(Ssum + 9), 1);   // scal[9]: wave counter
      if (old == 4159) {
        float S = atomicAdd(Ssum, 0.f);
        out[1048576] = -(S / 16777216.0f);
      }
    }
  }
}

extern "C" void kernel_launch(void* const* d_in, const int* in_sizes, int n_in,
                              void* d_out, int out_size, void* d_ws, size_t ws_size,
                              hipStream_t stream) {
  const float* x    = (const float*)d_in[0];
  const float* Waux = (const float*)d_in[1];
  const float* baux = (const float*)d_in[2];
  const float* W    = (const float*)d_in[3];
  const float* bias = (const float*)d_in[4];
  float* out = (float*)d_out;

  char* ws = (char*)d_ws;
  __bf16* totalbf = (__bf16*)ws;                    // 8192*256*2 = 4,194,304 B
  float* sq      = (float*)(ws + 4194304);          // 8192 f32
  float* colsum  = (float*)(ws + 4227072);          // 256 f32
  float* scal    = (float*)(ws + 4228096);          // 16 f32

  // zero sq + colsum + scal (contiguous)
  hipMemsetAsync(ws + 4194304, 0, 32768 + 1024 + 64, stream);

  k_outs<<<dim3(4, 32), 256, 0, stream>>>(x, W, bias, totalbf, sq, colsum, scal);
  k_combine<<<1024, 256, 0, stream>>>(x, Waux, baux, totalbf, out);
  k_gram<<<1056, 256, 0, stream>>>(totalbf, sq, scal, scal, out);
}

// Round 5
// 195.147 us; speedup vs baseline: 1.9001x; 1.4429x over previous
//
#include <hip/hip_runtime.h>
#include <stdint.h>

typedef __attribute__((ext_vector_type(8))) __bf16 bf16x8;
typedef __attribute__((ext_vector_type(4))) __bf16 bf16x4;
typedef __attribute__((ext_vector_type(4))) float f32x4;

__device__ __forceinline__ void load16_to_lds(const __bf16* g, __bf16* l) {
  __builtin_amdgcn_global_load_lds(
      (const __attribute__((address_space(1))) void*)g,
      (__attribute__((address_space(3))) void*)l, 16, 0, 0);
}

// ws layout: totalbf[0..4194304), sq @4194304 (32768B), colsum @4227072 (1024B),
// scal @4228096 (64B): [1]=g4*log2e [3]=sumsq [8]=cnt_outs(int) [9]=cnt_gram(int)
// part @4228160: 16 slots spaced 32 floats (2048B)

// ---------------- outs GEMM: tile 32(M) x 128(N), 512 blocks, dbuf staging ----
// waves 2x2: wave = 16M x 64N, acc[1][4] (16 AGPR). BK=64, 8 chunks.
__global__ __launch_bounds__(256) void k_outs(const float* __restrict__ x,
                                              const float* __restrict__ W,
                                              const float* __restrict__ bias,
                                              __bf16* __restrict__ totalbf,
                                              float* __restrict__ sq,
                                              float* __restrict__ colsum,
                                              float* __restrict__ scal) {
  __shared__ __bf16 As[32][72];
  __shared__ __bf16 Bs[128][72];
  __shared__ float red[256];
  __shared__ int lastflag;
  const int bj = blockIdx.x;    // 0..3
  const int bi = blockIdx.y;    // 0..127
  const int t = threadIdx.x;
  const int wid = t >> 6, lane = t & 63;
  const int wr = wid >> 1, wc = wid & 1;
  const int n16 = lane & 15, q = lane >> 4;

  const int arow0 = bi * 32;
  const int brow0 = bj * 128;
  const int rA = t >> 3, cA = (t & 7) * 8;          // A: 32 rows x 64 cols
  const int rB = t >> 3, cB = (t & 7) * 8;          // B: 4 rounds of 32 rows

  f32x4 acc[4];
  f32x4 zero = {0.f, 0.f, 0.f, 0.f};
  for (int j = 0; j < 4; ++j) acc[j] = zero;

  float4 ar[2];
  float4 br[4][2];
  // prefetch chunk 0
  {
    const float* pa = x + (size_t)(arow0 + rA) * 512 + cA;
    ar[0] = *(const float4*)(pa);
    ar[1] = *(const float4*)(pa + 4);
    for (int p = 0; p < 4; ++p) {
      const float* pb = W + (size_t)(brow0 + p * 32 + rB) * 512 + cB;
      br[p][0] = *(const float4*)(pb);
      br[p][1] = *(const float4*)(pb + 4);
    }
  }

  for (int kc = 0; kc < 8; ++kc) {
    __syncthreads();   // previous chunk's readers done
    {
      bf16x8 va = {(__bf16)ar[0].x, (__bf16)ar[0].y, (__bf16)ar[0].z, (__bf16)ar[0].w,
                   (__bf16)ar[1].x, (__bf16)ar[1].y, (__bf16)ar[1].z, (__bf16)ar[1].w};
      *(bf16x8*)&As[rA][cA] = va;
      for (int p = 0; p < 4; ++p) {
        bf16x8 vb = {(__bf16)br[p][0].x, (__bf16)br[p][0].y, (__bf16)br[p][0].z, (__bf16)br[p][0].w,
                     (__bf16)br[p][1].x, (__bf16)br[p][1].y, (__bf16)br[p][1].z, (__bf16)br[p][1].w};
        *(bf16x8*)&Bs[p * 32 + rB][cB] = vb;
      }
    }
    if (kc < 7) {   // prefetch next chunk; overlaps compute below
      const float* pa = x + (size_t)(arow0 + rA) * 512 + (kc + 1) * 64 + cA;
      ar[0] = *(const float4*)(pa);
      ar[1] = *(const float4*)(pa + 4);
      for (int p = 0; p < 4; ++p) {
        const float* pb = W + (size_t)(brow0 + p * 32 + rB) * 512 + (kc + 1) * 64 + cB;
        br[p][0] = *(const float4*)(pb);
        br[p][1] = *(const float4*)(pb + 4);
      }
    }
    __syncthreads();   // LDS ready
    for (int ks = 0; ks < 2; ++ks) {
      bf16x8 af = *(const bf16x8*)&As[wr * 16 + n16][ks * 32 + q * 8];
      for (int fc = 0; fc < 4; ++fc) {
        bf16x8 bfr = *(const bf16x8*)&Bs[wc * 64 + fc * 16 + n16][ks * 32 + q * 8];
        acc[fc] = __builtin_amdgcn_mfma_f32_16x16x32_bf16(af, bfr, acc[fc], 0, 0, 0);
      }
    }
  }

  // epilogue: +bias, bf16 store, fused sq / colsum / sumsq
  const int l = bj >> 1, oc0 = (bj & 1) * 128;
  float bv[4];
  for (int fc = 0; fc < 4; ++fc)
    bv[fc] = bias[bj * 128 + wc * 64 + fc * 16 + n16];

  float lane_ss = 0.f;
  float colpart[4] = {0.f, 0.f, 0.f, 0.f};
  for (int r = 0; r < 4; ++r) {
    int mrow = arow0 + wr * 16 + q * 4 + r;
    float rowpart = 0.f;
    for (int fc = 0; fc < 4; ++fc) {
      int o = oc0 + wc * 64 + fc * 16 + n16;
      float v = acc[fc][r] + bv[fc];
      __bf16 h = (__bf16)v;
      totalbf[(size_t)(l * 4096 + mrow) * 256 + o] = h;
      float vr = (float)h;
      rowpart += vr * vr;
      lane_ss += vr * vr;
      colpart[fc] += vr;
    }
    for (int off = 1; off < 16; off <<= 1) rowpart += __shfl_xor(rowpart, off, 64);
    if (n16 == 0) atomicAdd(&sq[l * 4096 + mrow], rowpart);
  }
  for (int fc = 0; fc < 4; ++fc) {
    colpart[fc] += __shfl_xor(colpart[fc], 16, 64);
    colpart[fc] += __shfl_xor(colpart[fc], 32, 64);
  }
  if (q == 0)
    for (int fc = 0; fc < 4; ++fc)
      atomicAdd(&colsum[oc0 + wc * 64 + fc * 16 + n16], colpart[fc]);
  for (int off = 1; off < 64; off <<= 1) lane_ss += __shfl_xor(lane_ss, off, 64);
  if (lane == 0) atomicAdd(&scal[3], lane_ss);

  __threadfence();
  __syncthreads();
  if (t == 0) lastflag = (atomicAdd((int*)&scal[8], 1) == 511);
  __syncthreads();
  if (lastflag) {
    float c = atomicAdd(&colsum[t], 0.f);
    red[t] = c * c;
    __syncthreads();
    for (int off = 128; off; off >>= 1) { if (t < off) red[t] += red[t + off]; __syncthreads(); }
    if (t == 0) {
      float sumsq = atomicAdd(&scal[3], 0.f);
      double sumdist = 2.0 * 8192.0 * (double)sumsq - 2.0 * (double)red[0];
      double bw = sumdist / (8192.0 * 8192.0 - 8192.0) / 4.0;  // / KERNEL_MUL^(5//2)
      scal[1] = (float)(1.4426950408889634 / (bw * 16.0));     // g4 * log2(e)
    }
  }
}

// ---------------- combine with fused gates: one wave per row ------------------
__global__ __launch_bounds__(256) void k_combine(const float* __restrict__ x,
                                                 const float* __restrict__ Waux,
                                                 const float* __restrict__ baux,
                                                 const __bf16* __restrict__ tot,
                                                 float* __restrict__ out) {
  const int wid = threadIdx.x >> 6;
  const int lane = threadIdx.x & 63;
  const int row = blockIdx.x * 4 + wid;
  const float4* xr = (const float4*)(x + (size_t)row * 512);
  const float4* w0 = (const float4*)(Waux);
  const float4* w1 = (const float4*)(Waux + 512);
  float p0 = 0.f, p1 = 0.f;
  for (int c = lane; c < 128; c += 64) {
    float4 xv = xr[c];
    float4 a = w0[c], b = w1[c];
    p0 += xv.x * a.x + xv.y * a.y + xv.z * a.z + xv.w * a.w;
    p1 += xv.x * b.x + xv.y * b.y + xv.z * b.z + xv.w * b.w;
  }
  for (int off = 1; off < 64; off <<= 1) {
    p0 += __shfl_xor(p0, off, 64);
    p1 += __shfl_xor(p1, off, 64);
  }
  p0 += baux[0]; p1 += baux[1];
  float m = fmaxf(p0, p1);
  float e0 = __expf(p0 - m), e1 = __expf(p1 - m);
  float inv = 1.f / (e0 + e1);
  float g0 = e0 * inv, g1 = e1 * inv;

  int oc = lane * 4;
  bf16x4 v0 = *(const bf16x4*)(tot + (size_t)row * 256 + oc);
  bf16x4 v1 = *(const bf16x4*)(tot + (size_t)(4096 + row) * 256 + oc);
  float4 r;
  r.x = g0 * (float)v0[0] + g1 * (float)v1[0];
  r.y = g0 * (float)v0[1] + g1 * (float)v1[1];
  r.z = g0 * (float)v0[2] + g1 * (float)v1[2];
  r.w = g0 * (float)v0[3] + g1 * (float)v1[3];
  *(float4*)(out + (size_t)row * 256 + oc) = r;
}

// ---------------- Gram + fused kernel sum: dbuf DMA staging, BK=32 ------------
// 2080 triangular blocks (ti<=tj over 64x64 tile grid of 128-row tiles).
// LDS layout: 8 groups of 16 rows per tile; group = 16 rows x 4 slots x 16B,
// slot s holds global col chunk (s ^ (row&3)) -> DMA-contiguous, read-bijective.
__global__ __launch_bounds__(256) void k_gram(const __bf16* __restrict__ tot,
                                              const float* __restrict__ sq,
                                              const float* __restrict__ scal,
                                              float* __restrict__ part,
                                              float* __restrict__ out) {
  __shared__ __bf16 As[2][128 * 32];   // 2 x 8 KB
  __shared__ __bf16 Bs[2][128 * 32];
  __shared__ float wred[4];
  const int t = threadIdx.x;
  const int wid = t >> 6, lane = t & 63;
  const int wr = wid >> 1, wc = wid & 1;
  const int n16 = lane & 15, q = lane >> 4;

  // triangular decode: blockIdx.x -> (ti, tj), ti <= tj
  int m = 2079 - (int)blockIdx.x;
  int n = (int)((sqrtf(8.f * (float)m + 1.f) - 1.f) * 0.5f);
  while ((n + 1) * (n + 2) / 2 <= m) ++n;
  while (n * (n + 1) / 2 > m) --n;
  const int ti = 63 - n;
  const int tj = 63 - (m - n * (n + 1) / 2);

  // DMA lane source: row-in-group lr, dest slot ls, source col chunk ls^(lr&3)
  const int g0 = wid * 2, g1 = wid * 2 + 1;   // groups staged by this wave
  const int lr = lane >> 2;
  const int sc = ((lane & 3) ^ (lr & 3)) * 8;
  const __bf16* a0 = tot + (size_t)(ti * 128 + g0 * 16 + lr) * 256 + sc;
  const __bf16* a1 = tot + (size_t)(ti * 128 + g1 * 16 + lr) * 256 + sc;
  const __bf16* b0 = tot + (size_t)(tj * 128 + g0 * 16 + lr) * 256 + sc;
  const __bf16* b1 = tot + (size_t)(tj * 128 + g1 * 16 + lr) * 256 + sc;

  f32x4 acc[4][4];
  f32x4 zero = {0.f, 0.f, 0.f, 0.f};
  for (int i = 0; i < 4; ++i)
    for (int j = 0; j < 4; ++j) acc[i][j] = zero;

  // prologue: DMA chunk 0 -> buf 0
  load16_to_lds(a0, &As[0][g0 * 512]);
  load16_to_lds(a1, &As[0][g1 * 512]);
  load16_to_lds(b0, &Bs[0][g0 * 512]);
  load16_to_lds(b1, &Bs[0][g1 * 512]);

  // within-group element offset for fragment reads
  const int ro = (n16 * 4 + (q ^ (n16 & 3))) * 8;

  for (int kc = 0; kc < 8; ++kc) {
    __syncthreads();   // drains DMA for chunk kc; prior readers of other buf done
    if (kc < 7) {      // prefetch chunk kc+1 into the other buffer
      const int nb = (kc + 1) & 1;
      const int off = (kc + 1) * 32;
      load16_to_lds(a0 + off, &As[nb][g0 * 512]);
      load16_to_lds(a1 + off, &As[nb][g1 * 512]);
      load16_to_lds(b0 + off, &Bs[nb][g0 * 512]);
      load16_to_lds(b1 + off, &Bs[nb][g1 * 512]);
    }
    const int cb = kc & 1;
    bf16x8 af[4], bfr[4];
    for (int f = 0; f < 4; ++f) {
      af[f]  = *(const bf16x8*)&As[cb][(wr * 4 + f) * 512 + ro];
      bfr[f] = *(const bf16x8*)&Bs[cb][(wc * 4 + f) * 512 + ro];
    }
    for (int fr = 0; fr < 4; ++fr)
      for (int fc = 0; fc < 4; ++fc)
        acc[fr][fc] = __builtin_amdgcn_mfma_f32_16x16x32_bf16(af[fr], bfr[fc], acc[fr][fc], 0, 0, 0);
  }

  // epilogue: u = exp2(fma(2g, dot, -(g)(si+sj))); ksum = u+u^2+u^4+u^8+u^16
  const float g = scal[1];
  const float g2 = 2.f * g;
  float cj[4];
  for (int fc = 0; fc < 4; ++fc)
    cj[fc] = -g * sq[tj * 128 + wc * 64 + fc * 16 + n16];

  float lsum = 0.f;
  for (int fr = 0; fr < 4; ++fr) {
    for (int r = 0; r < 4; ++r) {
      float ci = -g * sq[ti * 128 + wr * 64 + fr * 16 + q * 4 + r];
      for (int fc = 0; fc < 4; ++fc) {
        float p = fmaf(g2, acc[fr][fc][r], ci + cj[fc]);
        float u = exp2f(p);
        float u2 = u * u, u4 = u2 * u2, u8 = u4 * u4, u16 = u8 * u8;
        lsum += ((u + u2) + (u4 + u8)) + u16;
      }
    }
  }
  for (int off = 1; off < 64; off <<= 1) lsum += __shfl_xor(lsum, off, 64);
  if (lane == 0) wred[wid] = lsum;
  __syncthreads();
  if (t == 0) {
    float blocksum = wred[0] + wred[1] + wred[2] + wred[3];
    float sgn = ((ti < 32) == (tj < 32)) ? 1.f : -1.f;
    float wgt = (ti == tj) ? sgn : 2.f * sgn;
    atomicAdd(&part[(blockIdx.x & 15) * 32], wgt * blocksum);  // 16 spread slots
    __threadfence();
    int old = atomicAdd((int*)(part - 2), 1);   // scal[9] (part = scal+16... see host)
    if (old == 2079) {
      float S = 0.f;
      for (int s = 0; s < 16; ++s) S += atomicAdd(&part[s * 32], 0.f);
      out[1048576] = -(S / 16777216.0f);
    }
  }
}

extern "C" void kernel_launch(void* const* d_in, const int* in_sizes, int n_in,
                              void* d_out, int out_size, void* d_ws, size_t ws_size,
                              hipStream_t stream) {
  const float* x    = (const float*)d_in[0];
  const float* Waux = (const float*)d_in[1];
  const float* baux = (const float*)d_in[2];
  const float* W    = (const float*)d_in[3];
  const float* bias = (const float*)d_in[4];
  float* out = (float*)d_out;

  char* ws = (char*)d_ws;
  __bf16* totalbf = (__bf16*)ws;                    // 4,194,304 B
  float* sq      = (float*)(ws + 4194304);          // 8192 f32
  float* colsum  = (float*)(ws + 4227072);          // 256 f32
  float* scal    = (float*)(ws + 4228096);          // 16 f32; [9]=gram counter
  float* part    = (float*)(ws + 4228160);          // 16 slots x 32 f32 (2 KB)
  // note: part - 2 == &scal[14]... must match k_gram's counter deref:
  // k_gram uses (int*)(part - 2) => &scal[14]. Zeroed below.

  // zero sq + colsum + scal + part (contiguous from 4194304)
  hipMemsetAsync(ws + 4194304, 0, 32768 + 1024 + 64 + 2048, stream);

  k_outs<<<dim3(4, 128), 256, 0, stream>>>(x, W, bias, totalbf, sq, colsum, scal);
  k_combine<<<1024, 256, 0, stream>>>(x, Waux, baux, totalbf, out);
  k_gram<<<2080, 256, 0, stream>>>(totalbf, sq, scal, part, out);
}